// Round 7
// baseline (163.446 us; speedup 1.0000x reference)
//
#include <hip/hip_runtime.h>

#define BATCH 8192
#define INC   512
#define OUTC  512
#define NB    8
#define KDIM  (INC * NB)        // 4096
#define SPLITK 2
#define KH    (KDIM / SPLITK)   // 2048 k per block
#define IPB   (INC / SPLITK)    // 256 i per block
#define BM 128
#define BN 128
#define BK 64
#define NKT (KH / BK)           // 32
#define THREADS 256
#define BBUF (BN * BK)          // 8192 shorts = 16 KB

typedef __attribute__((ext_vector_type(8))) short bf16x8;
typedef __attribute__((ext_vector_type(4))) float f32x4;
typedef __attribute__((ext_vector_type(4))) int   i32x4;

// truncate-pack two fp32 into two bf16 (lo -> low 16 bits)
static __device__ __forceinline__ unsigned int pk2(float lo, float hi) {
    return __builtin_amdgcn_perm(__builtin_bit_cast(unsigned int, hi),
                                 __builtin_bit_cast(unsigned int, lo),
                                 0x07060302u);
}

// one A fragment = 8 basis values of one (b,i), in registers (validated r4/r5)
static __device__ __forceinline__ bf16x8 sigfrag(float x, float pc, float q0, float R) {
    float e = __builtin_amdgcn_exp2f(fmaf(pc, x, q0));
    float s[NB];
#pragma unroll
    for (int m = 0; m < NB; ++m) {
        s[m] = __builtin_amdgcn_rcpf(1.0f + e);
        e *= R;
    }
    return __builtin_bit_cast(bf16x8,
        (i32x4){(int)pk2(s[0], s[1]), (int)pk2(s[2], s[3]),
                (int)pk2(s[4], s[5]), (int)pk2(s[6], s[7])});
}

// ---- prepass 1: W fp32 -> bf16 (RNE) ----
__global__ __launch_bounds__(256)
void w_prepass(const float* __restrict__ W, unsigned short* __restrict__ Wb) {
    const int base = (blockIdx.x * 256 + threadIdx.x) * 8;
    const float4 a = *(const float4*)(W + base);
    const float4 b = *(const float4*)(W + base + 4);
    const float v[8] = {a.x, a.y, a.z, a.w, b.x, b.y, b.z, b.w};
    unsigned int r[8];
#pragma unroll
    for (int i = 0; i < 8; ++i) {
        unsigned int t = __builtin_bit_cast(unsigned int, v[i]);
        t += 0x7FFFu + ((t >> 16) & 1u);
        r[i] = t >> 16;
    }
    *(i32x4*)(Wb + base) = (i32x4){(int)(r[0] | (r[1] << 16)), (int)(r[2] | (r[3] << 16)),
                                   (int)(r[4] | (r[5] << 16)), (int)(r[6] | (r[7] << 16))};
}

// ---- prepass 2: X (BATCH,INC) -> XT (INC,BATCH) fp32 ----
__global__ __launch_bounds__(256)
void xt_prepass(const float* __restrict__ X, float* __restrict__ XT) {
    __shared__ float t[64][65];
    const int bx = blockIdx.x * 64;
    const int iy = blockIdx.y * 64;
    const int lx = threadIdx.x & 63;
    const int ly = threadIdx.x >> 6;
#pragma unroll
    for (int r = 0; r < 16; ++r) {
        const int row = ly * 16 + r;
        t[row][lx] = X[(size_t)(bx + row) * INC + iy + lx];
    }
    __syncthreads();
#pragma unroll
    for (int r = 0; r < 16; ++r) {
        const int row = ly * 16 + r;
        XT[(size_t)(iy + row) * BATCH + bx + lx] = t[lx][row];
    }
}

// B LDS layout (XOR-swizzled, verified r3/r6): element (row 0..127, kblk 0..7)
// at short offset row*64 + (kblk ^ (row&7))*8.
template <bool DMA, bool XTP>
__global__ __launch_bounds__(THREADS, 2)
void fused_gemm(const float* __restrict__ X,    // (BATCH, INC)
                const void*  __restrict__ Wsrc, // bf16 ws or fp32 W
                const float* __restrict__ XT,   // (INC, BATCH) or null
                const float* __restrict__ CEN,
                const float* __restrict__ SLP,
                float* __restrict__ Y)          // (BATCH, OUTC), pre-zeroed
{
    __shared__ short Bs[2][BBUF];   // 2 x 16 KB  (B only — A lives in registers)

    const int tid  = threadIdx.x;
    const int lane = tid & 63;
    const int wave = tid >> 6;      // 0..3
    const int wm   = wave & 1;      // 2 m-waves of 64 rows
    const int wn   = wave >> 1;     // 2 n-waves of 64 cols
    const int l15  = lane & 15;
    const int h    = lane >> 4;     // 0..3
    const int low3 = lane & 7;

    const int b0 = blockIdx.x * BM;
    const int j0 = blockIdx.y * BN;
    const int kz = blockIdx.z;
    const int i0 = kz * IPB;

    // sigmoid: s_m(x) = 1/(1 + exp2(pc*x + q0) * R^m)
    const float L2E = 1.4426950408889634f;
    const float g2  = 2.0f * SLP[0] * L2E;
    const float pc  = -g2;
    const float q0  = g2 * CEN[0];
    const float R   = __builtin_amdgcn_exp2f(g2 * (CEN[1] - CEN[0]));

    // B fragment read bases (XOR swizzle)
    const short* const brp0 = &Bs[0][(wn * 64 + l15) * 64 + ((0 + h) ^ low3) * 8];
    const short* const brp1 = &Bs[0][(wn * 64 + l15) * 64 + ((4 + h) ^ low3) * 8];

    // DMA global-side swizzle
    const int dma_r  = lane >> 3;
    const int dma_kb = (lane & 7) ^ dma_r;

    f32x4 acc[4][4];
#pragma unroll
    for (int i = 0; i < 4; ++i)
#pragma unroll
        for (int j = 0; j < 4; ++j)
            acc[i][j] = (f32x4){0.f, 0.f, 0.f, 0.f};

    float xv[8], xn[8];   // [ks*4 + mf] : x for this lane's 8 evals per k-tile

#define LOADX(kt, dst)                                                         \
    {                                                                          \
        _Pragma("unroll")                                                      \
        for (int ks = 0; ks < 2; ++ks) {                                       \
            const int ii = i0 + (kt) * 8 + ks * 4 + h;                         \
            _Pragma("unroll")                                                  \
            for (int mf = 0; mf < 4; ++mf) {                                   \
                const int bb = b0 + wm * 64 + mf * 16 + l15;                   \
                (dst)[ks * 4 + mf] = XTP ? XT[(size_t)ii * BATCH + bb]         \
                                         : X[(size_t)bb * INC + ii];           \
            }                                                                  \
        }                                                                      \
    }

#define STAGEB(kt, buf)                                                        \
    {                                                                          \
        const int kg = kz * KH + (kt) * BK;                                    \
        if constexpr (DMA) {                                                   \
            const unsigned short* Wb = (const unsigned short*)Wsrc;            \
            _Pragma("unroll")                                                  \
            for (int q = 0; q < 4; ++q) {                                      \
                const int cc = wave * 4 + q;   /* 1 KB chunk, wave-uniform */  \
                const unsigned short* gp = Wb                                  \
                    + (size_t)(j0 + cc * 8 + dma_r) * KDIM + kg + dma_kb * 8;  \
                __builtin_amdgcn_global_load_lds(                              \
                    (const __attribute__((address_space(1))) void*)gp,         \
                    (__attribute__((address_space(3))) void*)(&Bs[buf][cc * 512]), \
                    16, 0, 0);                                                 \
            }                                                                  \
        } else {                                                               \
            const float* Wf = (const float*)Wsrc;                              \
            const int row = tid >> 1;                                          \
            const int q4  = tid & 1;                                           \
            const float* wp = Wf + (size_t)(j0 + row) * KDIM + kg + q4 * 32;   \
            _Pragma("unroll")                                                  \
            for (int p = 0; p < 4; ++p) {                                      \
                const int kb = q4 * 4 + p;                                     \
                const float4 c0 = ((const float4*)wp)[2 * p];                  \
                const float4 c1 = ((const float4*)wp)[2 * p + 1];              \
                *(i32x4*)(&Bs[buf][row * 64 + ((kb ^ (row & 7)) * 8)]) =       \
                    (i32x4){(int)pk2(c0.x, c0.y), (int)pk2(c0.z, c0.w),        \
                            (int)pk2(c1.x, c1.y), (int)pk2(c1.z, c1.w)};       \
            }                                                                  \
        }                                                                      \
    }

    // ---- prologue ----
    LOADX(0, xv);
    STAGEB(0, 0);
    bf16x8 afA[4];                       // A frags for the upcoming ks=0 half
#pragma unroll
    for (int mf = 0; mf < 4; ++mf)
        afA[mf] = sigfrag(xv[mf], pc, q0, R);
    LOADX(1, xn);

    for (int kt = 0; kt < NKT; ++kt) {
        const int cur = kt & 1;

        __syncthreads();   // buf[cur] staged; prior reads of buf[1-cur] done

        if (kt + 1 < NKT) STAGEB(kt + 1, 1 - cur);   // DMA under this iter's MFMAs

        // ---- ks = 0 : MFMAs use afA (ready); build afB for ks=1 meanwhile ----
        bf16x8 bf0[4];
#pragma unroll
        for (int nf = 0; nf < 4; ++nf)
            bf0[nf] = *(const bf16x8*)(brp0 + cur * BBUF + nf * 1024);

        bf16x8 afB[4];
#pragma unroll
        for (int mf = 0; mf < 4; ++mf)
            afB[mf] = sigfrag(xv[4 + mf], pc, q0, R);

#pragma unroll
        for (int mf = 0; mf < 4; ++mf)
#pragma unroll
            for (int nf = 0; nf < 4; ++nf)
                acc[mf][nf] = __builtin_amdgcn_mfma_f32_16x16x32_bf16(
                    afA[mf], bf0[nf], acc[mf][nf], 0, 0, 0);

        // ---- ks = 1 : MFMAs use afB; build next iter's afA meanwhile ----
        bf16x8 bf1[4];
#pragma unroll
        for (int nf = 0; nf < 4; ++nf)
            bf1[nf] = *(const bf16x8*)(brp1 + cur * BBUF + nf * 1024);

#pragma unroll
        for (int mf = 0; mf < 4; ++mf)
            afA[mf] = sigfrag(xn[mf], pc, q0, R);

#pragma unroll
        for (int mf = 0; mf < 4; ++mf)
#pragma unroll
            for (int nf = 0; nf < 4; ++nf)
                acc[mf][nf] = __builtin_amdgcn_mfma_f32_16x16x32_bf16(
                    afB[mf], bf1[nf], acc[mf][nf], 0, 0, 0);

        // rotate x pipeline
#pragma unroll
        for (int q = 0; q < 8; ++q) xv[q] = xn[q];
        const int ktn = (kt + 2 < NKT) ? (kt + 2) : (NKT - 1);
        LOADX(ktn, xn);
    }
#undef LOADX
#undef STAGEB

    // epilogue: C/D layout col=lane&15, row=(lane>>4)*4+reg ; accumulate across kz
    const int rowb = b0 + wm * 64 + h * 4;
    const int colb = j0 + wn * 64 + l15;
#pragma unroll
    for (int mf = 0; mf < 4; ++mf)
#pragma unroll
        for (int nf = 0; nf < 4; ++nf)
#pragma unroll
            for (int r = 0; r < 4; ++r)
                atomicAdd(&Y[(size_t)(rowb + mf * 16 + r) * OUTC + (colb + nf * 16)],
                          acc[mf][nf][r]);
}

extern "C" void kernel_launch(void* const* d_in, const int* in_sizes, int n_in,
                              void* d_out, int out_size, void* d_ws, size_t ws_size,
                              hipStream_t stream) {
    const float* X   = (const float*)d_in[0];
    const float* W   = (const float*)d_in[1];
    const float* CEN = (const float*)d_in[2];
    const float* SLP = (const float*)d_in[3];
    float* Y = (float*)d_out;

    hipMemsetAsync(d_out, 0, (size_t)out_size * sizeof(float), stream);

    static_assert(BATCH % BM == 0 && OUTC % BN == 0 && KH % BK == 0, "tiling");
    dim3 grid(BATCH / BM, OUTC / BN, SPLITK);   // 64 x 4 x 2 = 512 blocks

    const size_t WB_BYTES = (size_t)OUTC * KDIM * sizeof(unsigned short); // 4 MB
    const size_t XT_BYTES = (size_t)BATCH * INC * sizeof(float);          // 16 MB

    if (ws_size >= WB_BYTES + XT_BYTES) {
        unsigned short* Wb = (unsigned short*)d_ws;
        float* XT = (float*)((char*)d_ws + WB_BYTES);
        w_prepass<<<dim3((OUTC * KDIM) / (8 * 256)), dim3(256), 0, stream>>>(W, Wb);
        xt_prepass<<<dim3(BATCH / 64, INC / 64), dim3(256), 0, stream>>>(X, XT);
        fused_gemm<true, true><<<grid, dim3(THREADS), 0, stream>>>(
            X, Wb, XT, CEN, SLP, Y);
    } else if (ws_size >= WB_BYTES) {
        unsigned short* Wb = (unsigned short*)d_ws;
        w_prepass<<<dim3((OUTC * KDIM) / (8 * 256)), dim3(256), 0, stream>>>(W, Wb);
        fused_gemm<true, false><<<grid, dim3(THREADS), 0, stream>>>(
            X, Wb, nullptr, CEN, SLP, Y);
    } else {
        fused_gemm<false, false><<<grid, dim3(THREADS), 0, stream>>>(
            X, (const void*)W, nullptr, CEN, SLP, Y);
    }
}

// Round 8
// 140.016 us; speedup vs baseline: 1.1673x; 1.1673x over previous
//
#include <hip/hip_runtime.h>

#define BATCH 8192
#define INC   512
#define OUTC  512
#define NB    8
#define KDIM  (INC * NB)        // 4096
#define SPLITK 2
#define KH    (KDIM / SPLITK)   // 2048 k per block
#define IPB   (INC / SPLITK)    // 256 i per block
#define BM 128
#define BN 128
#define BK 64
#define NKT (KH / BK)           // 32
#define THREADS 256
#define ABUF (BM * BK)          // 8192 shorts = 16 KB
#define BBUF (BN * BK)          // 16 KB

typedef __attribute__((ext_vector_type(8)))  short bf16x8;
typedef __attribute__((ext_vector_type(16))) float f32x16;
typedef __attribute__((ext_vector_type(4)))  int   i32x4;

// truncate-pack two fp32 into two bf16 (lo -> low 16 bits)
static __device__ __forceinline__ unsigned int pk2(float lo, float hi) {
    return __builtin_amdgcn_perm(__builtin_bit_cast(unsigned int, hi),
                                 __builtin_bit_cast(unsigned int, lo),
                                 0x07060302u);
}

// ---- prepass: W fp32 -> bf16 (RNE) ----
__global__ __launch_bounds__(256)
void w_prepass(const float* __restrict__ W, unsigned short* __restrict__ Wb) {
    const int base = (blockIdx.x * 256 + threadIdx.x) * 8;
    const float4 a = *(const float4*)(W + base);
    const float4 b = *(const float4*)(W + base + 4);
    const float v[8] = {a.x, a.y, a.z, a.w, b.x, b.y, b.z, b.w};
    unsigned int r[8];
#pragma unroll
    for (int i = 0; i < 8; ++i) {
        unsigned int t = __builtin_bit_cast(unsigned int, v[i]);
        t += 0x7FFFu + ((t >> 16) & 1u);
        r[i] = t >> 16;
    }
    *(i32x4*)(Wb + base) = (i32x4){(int)(r[0] | (r[1] << 16)), (int)(r[2] | (r[3] << 16)),
                                   (int)(r[4] | (r[5] << 16)), (int)(r[6] | (r[7] << 16))};
}

// LDS layout for BOTH A and B (XOR-swizzled, verified r3/r6):
//   element (row, kblk 0..7) at short offset row*64 + (kblk ^ (row&7))*8
template <bool DMA>
__global__ __launch_bounds__(THREADS, 2)
void fused_gemm(const float* __restrict__ X,    // (BATCH, INC)
                const void*  __restrict__ Wsrc, // bf16 ws or fp32 W
                const float* __restrict__ CEN,
                const float* __restrict__ SLP,
                float* __restrict__ Y)          // (BATCH, OUTC), pre-zeroed
{
    __shared__ short As[ABUF];   // 16 KB, single-buffered (r3 two-barrier scheme)
    __shared__ short Bs[BBUF];   // 16 KB

    const int tid  = threadIdx.x;
    const int lane = tid & 63;
    const int wave = tid >> 6;      // 0..3
    const int wm   = wave & 1;      // m-half: 64 rows
    const int wn   = wave >> 1;     // n-half: 64 cols
    const int l31  = lane & 31;
    const int h8   = lane >> 5;     // 0..1 : k-half within K16

    const int b0 = blockIdx.x * BM;
    const int j0 = blockIdx.y * BN;
    const int kz = blockIdx.z;
    const int i0 = kz * IPB;

    // sigmoid: s_m(x) = 1/(1 + exp2(pc*x + q0) * R^m)
    const float L2E = 1.4426950408889634f;
    const float g2  = 2.0f * SLP[0] * L2E;
    const float pc  = -g2;
    const float q0  = g2 * CEN[0];
    const float R   = __builtin_amdgcn_exp2f(g2 * (CEN[1] - CEN[0]));

    // DMA global-side swizzle (verified r3/r6/r7)
    const int dma_r  = lane >> 3;
    const int dma_kb = (lane & 7) ^ dma_r;

    // A staging role: thread -> (row 0..127, 4 of 8 kblks), r6-verified
    const int srow = tid >> 1;
    const int sib  = (tid & 1) * 4;
    const int sxor = srow & 7;
    const float* xrow = X + (size_t)(b0 + srow) * INC + i0 + sib;

    // fragment read bases: A rows (m), B rows (n); 32x32x16 frag:
    //   A[m = lane&31][k = h8*8 + j]  (16x16 pattern scaled; verify via bench)
    int arow[2], brow[2];
#pragma unroll
    for (int f = 0; f < 2; ++f) {
        arow[f] = wm * 64 + f * 32 + l31;
        brow[f] = wn * 64 + f * 32 + l31;
    }

    f32x16 acc[2][2];
#pragma unroll
    for (int i = 0; i < 2; ++i)
#pragma unroll
        for (int j = 0; j < 2; ++j)
            acc[i][j] = (f32x16)(0.0f);

    float4 xc = *(const float4*)(xrow);   // x for kt = 0

    for (int kt = 0; kt < NKT; ++kt) {
        // ---- stage(kt): DMA B + sigmoid -> A LDS ----
        if constexpr (DMA) {
            const unsigned short* Wb = (const unsigned short*)Wsrc;
#pragma unroll
            for (int q = 0; q < 4; ++q) {
                const int cc = wave * 4 + q;   // 1 KB chunk, wave-uniform
                const unsigned short* gp = Wb
                    + (size_t)(j0 + cc * 8 + dma_r) * KDIM + kz * KH
                    + kt * BK + dma_kb * 8;
                __builtin_amdgcn_global_load_lds(
                    (const __attribute__((address_space(1))) void*)gp,
                    (__attribute__((address_space(3))) void*)(&Bs[cc * 512]),
                    16, 0, 0);
            }
        } else {
            const float* Wf = (const float*)Wsrc;
            const int row = tid >> 1;
            const int q4  = tid & 1;
            const float* wp = Wf + (size_t)(j0 + row) * KDIM + kz * KH
                            + kt * BK + q4 * 32;
#pragma unroll
            for (int p = 0; p < 4; ++p) {
                const int kb = q4 * 4 + p;
                const float4 c0 = ((const float4*)wp)[2 * p];
                const float4 c1 = ((const float4*)wp)[2 * p + 1];
                *(i32x4*)(&Bs[row * 64 + ((kb ^ (row & 7)) * 8)]) =
                    (i32x4){(int)pk2(c0.x, c0.y), (int)pk2(c0.z, c0.w),
                            (int)pk2(c1.x, c1.y), (int)pk2(c1.z, c1.w)};
            }
        }
        {
            const float xe[4] = {xc.x, xc.y, xc.z, xc.w};
#pragma unroll
            for (int e = 0; e < 4; ++e) {
                float ev = __builtin_amdgcn_exp2f(fmaf(pc, xe[e], q0));
                float s[NB];
#pragma unroll
                for (int m = 0; m < NB; ++m) {
                    s[m] = __builtin_amdgcn_rcpf(1.0f + ev);
                    ev *= R;
                }
                *(i32x4*)(&As[srow * 64 + (((sib + e) ^ sxor) * 8)]) =
                    (i32x4){(int)pk2(s[0], s[1]), (int)pk2(s[2], s[3]),
                            (int)pk2(s[4], s[5]), (int)pk2(s[6], s[7])};
            }
        }

        __syncthreads();   // barrier 1: staging visible (drains DMA + ds_write)

        // x prefetch for kt+1 — latency hidden under the MFMA phase
        const int ktn = (kt + 1 < NKT) ? (kt + 1) : (NKT - 1);
        const float4 xn = *(const float4*)(xrow + ktn * 8);

        // ---- MFMA phase: 4 K16-steps, 2x2 frags of 32x32x16 ----
#pragma unroll
        for (int ks = 0; ks < 4; ++ks) {
            bf16x8 af[2], bf[2];
#pragma unroll
            for (int f = 0; f < 2; ++f) {
                const int kb = ks * 2 + h8;
                af[f] = *(const bf16x8*)(&As[arow[f] * 64 + ((kb ^ (arow[f] & 7)) * 8)]);
                bf[f] = *(const bf16x8*)(&Bs[brow[f] * 64 + ((kb ^ (brow[f] & 7)) * 8)]);
            }
#pragma unroll
            for (int fm = 0; fm < 2; ++fm)
#pragma unroll
                for (int fn = 0; fn < 2; ++fn)
                    acc[fm][fn] = __builtin_amdgcn_mfma_f32_32x32x16_bf16(
                        af[fm], bf[fn], acc[fm][fn], 0, 0, 0);
        }

        __syncthreads();   // barrier 2: reads done before next stage overwrites

        xc = xn;
    }

    // ---- epilogue: 32x32 C/D layout col=lane&31, row=(r&3)+8*(r>>2)+4*h8
    //      (verified m74/m101); accumulate across kz via atomics ----
#pragma unroll
    for (int fm = 0; fm < 2; ++fm)
#pragma unroll
        for (int fn = 0; fn < 2; ++fn) {
            const int colg = j0 + wn * 64 + fn * 32 + l31;
#pragma unroll
            for (int r = 0; r < 16; ++r) {
                const int rowg = b0 + wm * 64 + fm * 32
                               + (r & 3) + 8 * (r >> 2) + 4 * h8;
                atomicAdd(&Y[(size_t)rowg * OUTC + colg], acc[fm][fn][r]);
            }
        }
}

extern "C" void kernel_launch(void* const* d_in, const int* in_sizes, int n_in,
                              void* d_out, int out_size, void* d_ws, size_t ws_size,
                              hipStream_t stream) {
    const float* X   = (const float*)d_in[0];
    const float* W   = (const float*)d_in[1];
    const float* CEN = (const float*)d_in[2];
    const float* SLP = (const float*)d_in[3];
    float* Y = (float*)d_out;

    hipMemsetAsync(d_out, 0, (size_t)out_size * sizeof(float), stream);

    static_assert(BATCH % BM == 0 && OUTC % BN == 0 && KH % BK == 0, "tiling");
    dim3 grid(BATCH / BM, OUTC / BN, SPLITK);   // 64 x 4 x 2 = 512 blocks

    const size_t WB_BYTES = (size_t)OUTC * KDIM * sizeof(unsigned short); // 4 MB
    if (ws_size >= WB_BYTES) {
        unsigned short* Wb = (unsigned short*)d_ws;
        w_prepass<<<dim3((OUTC * KDIM) / (8 * 256)), dim3(256), 0, stream>>>(W, Wb);
        fused_gemm<true><<<grid, dim3(THREADS), 0, stream>>>(X, Wb, CEN, SLP, Y);
    } else {
        fused_gemm<false><<<grid, dim3(THREADS), 0, stream>>>(X, (const void*)W,
                                                              CEN, SLP, Y);
    }
}